// Round 3
// baseline (606.464 us; speedup 1.0000x reference)
//
#include <hip/hip_runtime.h>
#include <math.h>

#define NIMG 8
#define CIN 8
#define Hh 136
#define Ww 200
#define HW (Hh * Ww)
#define OH 272
#define OW 400
#define NINST 512
#define NPAR 169
#define TROWS 34
#define NTILES 8
#define LROWS 19
#define PART_BYTES ((size_t)NINST * NTILES * 3 * 4)

#define PINV(x) asm volatile("" : "+v"(x))
#define PINS(x) asm volatile("" : "+s"(x))

// ---- single-pass per-tile MLP (round-0 verified quad structure) ----
// Computes logit rows [ly0, ly0+lycnt) straight into LDS slog.
// w1 lives in SGPRs (block-uniform; v_fmac takes one SGPR operand free),
// so peak VGPR ~170: no spill (round-1 bug) and no hbuf round-trip
// (round-2 overhead: 16 LDS ops + 8 scalar loads + idx math per px).
__device__ __forceinline__ void mlp_tile(
    float* __restrict__ slog, const float* __restrict__ fb0,
    int ly0, int lycnt, int tid,
    const float (&Wf)[64], const float (&w1)[64], const float (&w2)[8],
    const float (&b1)[8], const float (&A0)[8], const float (&Ax)[8],
    const float (&Ay)[8], float b2)
{
    const int nq = lycnt * (Ww / 4);
    for (int q = tid; q < nq; q += 256) {
        const int yy = q / 50;
        const int xq = (q - yy * 50) * 4;
        const float yf = (float)(ly0 + yy);
        const float* fb = fb0 + (ly0 + yy) * Ww + xq;
        float f[8][4];
#pragma unroll
        for (int c = 0; c < 8; c++) {
            const float4 t = *reinterpret_cast<const float4*>(fb + c * HW);
            f[c][0] = t.x; f[c][1] = t.y; f[c][2] = t.z; f[c][3] = t.w;
        }
        float pre[8];
#pragma unroll
        for (int o = 0; o < 8; o++) pre[o] = A0[o] + Ay[o] * yf;

        float o4[4];
#pragma unroll
        for (int p = 0; p < 4; p++) {
            const float xf = (float)(xq + p);
            float h[8];
#pragma unroll
            for (int o = 0; o < 8; o++) {
                float a = pre[o] + Ax[o] * xf;
#pragma unroll
                for (int c = 0; c < 8; c++) a += Wf[o * 8 + c] * f[c][p];
                h[o] = fmaxf(a, 0.0f);
            }
            float g[8];
#pragma unroll
            for (int o = 0; o < 8; o++) {
                float a = b1[o];
#pragma unroll
                for (int c = 0; c < 8; c++) a += w1[o * 8 + c] * h[c];
                g[o] = fmaxf(a, 0.0f);
            }
            float lg = b2;
#pragma unroll
            for (int c = 0; c < 8; c++) lg += w2[c] * g[c];
            o4[p] = lg;
        }
        *reinterpret_cast<float4*>(&slog[yy * Ww + xq]) =
            make_float4(o4[0], o4[1], o4[2], o4[3]);
    }
}

// ---- per-tile bilinear-up + sigmoid + dice partials (identical to verified) ----
__device__ __forceinline__ void dice_tile(
    const float* __restrict__ slog, const float* __restrict__ gtn,
    int oy0, int ly0, int lycnt, int tid,
    float& aI, float& aS, float& aT)
{
    const float sy = 135.0f / 271.0f;
    const float sx = 199.0f / 399.0f;
    for (int g4 = tid; g4 < TROWS * (OW / 4); g4 += 256) {
        const int ry = g4 / 100;
        const int gx = (g4 - ry * 100) * 4;
        const int oy = oy0 + ry;
        const float ysf = (float)oy * sy;
        const int y0 = (int)ysf;
        const float wy = ysf - (float)y0;
        const int y1 = (y0 + 1 > Hh - 1) ? (Hh - 1) : (y0 + 1);
        int r0i = y0 - ly0, r1i = y1 - ly0;
        r0i = r0i < 0 ? 0 : (r0i > lycnt - 1 ? lycnt - 1 : r0i);
        r1i = r1i < 0 ? 0 : (r1i > lycnt - 1 ? lycnt - 1 : r1i);
        const float* s0 = &slog[r0i * Ww];
        const float* s1 = &slog[r1i * Ww];

        const float4 t4 = *reinterpret_cast<const float4*>(gtn + ry * OW + gx);
        const float tv[4] = { t4.x, t4.y, t4.z, t4.w };
#pragma unroll
        for (int p = 0; p < 4; p++) {
            const int ox = gx + p;
            const float xsf = (float)ox * sx;
            const int x0 = (int)xsf;
            const float wx = xsf - (float)x0;
            const int x1 = (x0 + 1 > Ww - 1) ? (Ww - 1) : (x0 + 1);
            const float v00 = s0[x0];
            const float v01 = s0[x1];
            const float v10 = s1[x0];
            const float v11 = s1[x1];
            const float top = v00 + wx * (v01 - v00);
            const float bot = v10 + wx * (v11 - v10);
            const float v   = top + wy * (bot - top);
            const float s   = __fdividef(1.0f, 1.0f + __expf(-v));
            aI += s * tv[p];
            aS += s * s;
            aT += tv[p];
        }
    }
}

// Params: Wf/affine/w2/b1/b2 pinned to VGPR (105), w1 pinned to SGPR (64).
#define LOAD_PARAMS                                                             \
    const float ix = iloc[2 * n + 0];                                           \
    const float iy = iloc[2 * n + 1];                                           \
    const int   im = iminds[n];                                                 \
    const float invsoi = 1.0f / (float)(64 << lvls[n]);                         \
    const float* pp = pars + n * NPAR;                                          \
    float Wf[64], w1[64], w2[8], b1[8], A0[8], Ax[8], Ay[8], b2;                \
    _Pragma("unroll")                                                           \
    for (int o = 0; o < 8; o++) {                                               \
        const float wx0 = pp[o * 10 + 0];                                       \
        const float wy0 = pp[o * 10 + 1];                                       \
        Ax[o] = -8.0f * invsoi * wx0;                                           \
        Ay[o] = -8.0f * invsoi * wy0;                                           \
        A0[o] = pp[152 + o] + (wx0 * (ix - 4.0f) + wy0 * (iy - 4.0f)) * invsoi; \
        _Pragma("unroll")                                                       \
        for (int c = 0; c < 8; c++) Wf[o * 8 + c] = pp[o * 10 + 2 + c];         \
    }                                                                           \
    _Pragma("unroll")                                                           \
    for (int i = 0; i < 64; i++) w1[i] = pp[80 + i];                            \
    _Pragma("unroll")                                                           \
    for (int i = 0; i < 8; i++)  w2[i] = pp[144 + i];                           \
    _Pragma("unroll")                                                           \
    for (int i = 0; i < 8; i++)  b1[i] = pp[160 + i];                           \
    b2 = pp[168];                                                               \
    _Pragma("unroll")                                                           \
    for (int i = 0; i < 64; i++) PINV(Wf[i]);                                   \
    _Pragma("unroll")                                                           \
    for (int i = 0; i < 64; i++) PINS(w1[i]);                                   \
    _Pragma("unroll")                                                           \
    for (int i = 0; i < 8; i++) { PINV(w2[i]); PINV(b1[i]); PINV(A0[i]);        \
                                  PINV(Ax[i]); PINV(Ay[i]); }                   \
    PINV(b2);

// ---------------- Fused: MLP -> LDS logits -> dice partials ----------------
__global__ __launch_bounds__(256, 1) void dmh_tile(
    const float* __restrict__ feats,
    const float* __restrict__ pars,
    const float* __restrict__ iloc,
    const float* __restrict__ gt,
    const int* __restrict__ iminds,
    const int* __restrict__ lvls,
    float* __restrict__ part)
{
    __shared__ float slog[LROWS * Ww];
    __shared__ float sred[12];

    const int n    = blockIdx.y;
    const int tile = blockIdx.x;
    const int tid  = threadIdx.x;

    LOAD_PARAMS

    const float sy = 135.0f / 271.0f;
    const int oy0 = tile * TROWS;
    const int ly0 = (int)((float)oy0 * sy);
    int lyL = (int)((float)(oy0 + TROWS - 1) * sy) + 1;
    if (lyL > Hh - 1) lyL = Hh - 1;
    const int lycnt = lyL - ly0 + 1;

    const float* fb0 = feats + (size_t)im * (CIN * HW);
    mlp_tile(slog, fb0, ly0, lycnt, tid, Wf, w1, w2, b1, A0, Ax, Ay, b2);
    __syncthreads();

    float aI = 0.0f, aS = 0.0f, aT = 0.0f;
    const float* gtn = gt + (size_t)n * (OH * OW) + (size_t)oy0 * OW;
    dice_tile(slog, gtn, oy0, ly0, lycnt, tid, aI, aS, aT);

#pragma unroll
    for (int off = 32; off > 0; off >>= 1) {
        aI += __shfl_down(aI, off, 64);
        aS += __shfl_down(aS, off, 64);
        aT += __shfl_down(aT, off, 64);
    }
    const int wv = tid >> 6;
    if ((tid & 63) == 0) {
        sred[wv * 3 + 0] = aI;
        sred[wv * 3 + 1] = aS;
        sred[wv * 3 + 2] = aT;
    }
    __syncthreads();
    if (tid == 0) {
        float* pt = part + (size_t)(n * NTILES + tile) * 3;
        pt[0] = sred[0] + sred[3] + sred[6] + sred[9];
        pt[1] = sred[1] + sred[4] + sred[7] + sred[10];
        pt[2] = sred[2] + sred[5] + sred[8] + sred[11];
    }
}

__global__ __launch_bounds__(256) void dmh_fin2(const float* __restrict__ part,
                                                float* __restrict__ out)
{
    const int i = blockIdx.x * 256 + threadIdx.x;
    if (i < NINST) {
        float I = 0.0f, S = 0.0f, T = 0.0f;
#pragma unroll
        for (int t = 0; t < NTILES; t++) {
            const float* pt = part + (size_t)(i * NTILES + t) * 3;
            I += pt[0]; S += pt[1]; T += pt[2];
        }
        out[i] = 1.0f - 2.0f * I / (S + T + 1e-5f);
    }
}

// ---- workspace-free fallback: one block per instance, loops over tiles ----
__global__ __launch_bounds__(256, 1) void dmh_one(
    const float* __restrict__ feats,
    const float* __restrict__ pars,
    const float* __restrict__ iloc,
    const float* __restrict__ gt,
    const int* __restrict__ iminds,
    const int* __restrict__ lvls,
    float* __restrict__ out)
{
    __shared__ float slog[LROWS * Ww];
    __shared__ float sred[12];

    const int n   = blockIdx.x;
    const int tid = threadIdx.x;

    LOAD_PARAMS

    const float sy = 135.0f / 271.0f;
    const float* fb0 = feats + (size_t)im * (CIN * HW);

    float aI = 0.0f, aS = 0.0f, aT = 0.0f;
    for (int tile = 0; tile < NTILES; tile++) {
        const int oy0 = tile * TROWS;
        const int ly0 = (int)((float)oy0 * sy);
        int lyL = (int)((float)(oy0 + TROWS - 1) * sy) + 1;
        if (lyL > Hh - 1) lyL = Hh - 1;
        const int lycnt = lyL - ly0 + 1;

        mlp_tile(slog, fb0, ly0, lycnt, tid, Wf, w1, w2, b1, A0, Ax, Ay, b2);
        __syncthreads();
        const float* gtn = gt + (size_t)n * (OH * OW) + (size_t)oy0 * OW;
        dice_tile(slog, gtn, oy0, ly0, lycnt, tid, aI, aS, aT);
        __syncthreads();  // slog reused next tile
    }

#pragma unroll
    for (int off = 32; off > 0; off >>= 1) {
        aI += __shfl_down(aI, off, 64);
        aS += __shfl_down(aS, off, 64);
        aT += __shfl_down(aT, off, 64);
    }
    const int wv = tid >> 6;
    if ((tid & 63) == 0) {
        sred[wv * 3 + 0] = aI;
        sred[wv * 3 + 1] = aS;
        sred[wv * 3 + 2] = aT;
    }
    __syncthreads();
    if (tid == 0) {
        const float I = sred[0] + sred[3] + sred[6] + sred[9];
        const float S = sred[1] + sred[4] + sred[7] + sred[10];
        const float T = sred[2] + sred[5] + sred[8] + sred[11];
        out[n] = 1.0f - 2.0f * I / (S + T + 1e-5f);
    }
}

extern "C" void kernel_launch(void* const* d_in, const int* in_sizes, int n_in,
                              void* d_out, int out_size, void* d_ws, size_t ws_size,
                              hipStream_t stream) {
    const float* feats  = (const float*)d_in[0];
    const float* pars   = (const float*)d_in[1];
    const float* iloc   = (const float*)d_in[2];
    const float* gt     = (const float*)d_in[3];
    const int*   iminds = (const int*)d_in[4];
    const int*   lvls   = (const int*)d_in[5];

    if (ws_size >= PART_BYTES) {
        float* part = (float*)d_ws;
        dim3 g(NTILES, NINST);
        dmh_tile<<<g, 256, 0, stream>>>(feats, pars, iloc, gt, iminds, lvls, part);
        dmh_fin2<<<(NINST + 255) / 256, 256, 0, stream>>>(part, (float*)d_out);
    } else {
        dmh_one<<<NINST, 256, 0, stream>>>(feats, pars, iloc, gt, iminds, lvls,
                                           (float*)d_out);
    }
}

// Round 4
// 400.800 us; speedup vs baseline: 1.5131x; 1.5131x over previous
//
#include <hip/hip_runtime.h>
#include <math.h>

#define NIMG 8
#define CIN 8
#define Hh 136
#define Ww 200
#define HW (Hh * Ww)
#define OH 272
#define OW 400
#define NINST 512
#define NPAR 169
#define TROWS 34
#define NTILES 8
#define LROWS 19
#define SQUADS 256                      // quads per strip (== blockDim)
#define PART_BYTES ((size_t)NINST * NTILES * 3 * 4)

#define PINV(x) asm volatile("" : "+v"(x))
#define PINS(x) asm volatile("" : "+s"(x))
#define MEMFENCE asm volatile("" ::: "memory")

// ---- two-pass quad MLP over flat 1024-px strips ----
// Pass A: layer0 (Wf in SGPRs) -> hbuf[o][quad*4+p] via ds_write_b128.
// Pass B: layer1+2 (w1 in SGPRs) -> slog via ds_write_b128.
// Wf and w1 are never live together -> each pass fits the SGPR budget and
// the VGPR file stays ~100 (R3 lesson: 192 VGPR -> 1 block/CU -> latency-bound).
// Ww=200 % 4 == 0 so no quad straddles a row; the tile region is contiguous
// per channel plane -> float4 feature loads, one div per quad.
// FP expression trees identical to the verified R0-R3 kernels (absmax 0.0).
__device__ __forceinline__ void mlp_tile_2pq(
    float* __restrict__ slog, float* __restrict__ hbuf,
    const float* __restrict__ fb0, const float* __restrict__ pp,
    int ly0, int lycnt, int tid,
    const float (&A0)[8], const float (&Ax)[8], const float (&Ay)[8])
{
    const int tq = lycnt * (Ww / 4);            // tile quads (<= 950)
    const float* fbase = fb0 + ly0 * Ww;        // contiguous tile region per plane

    for (int q0 = 0; q0 < tq; q0 += SQUADS) {
        const int q   = q0 + tid;
        const bool act = q < tq;

        // ---------- pass A: layer0 + relu -> hbuf ----------
        MEMFENCE;                                // keep Wf pass-local
        float Wf[64];
#pragma unroll
        for (int o = 0; o < 8; o++)
#pragma unroll
            for (int c = 0; c < 8; c++) Wf[o * 8 + c] = pp[o * 10 + 2 + c];
#pragma unroll
        for (int i = 0; i < 64; i++) PINS(Wf[i]);

        if (act) {
            const int px = q * 4;
            const int yy = px / 200;
            const int x  = px - yy * 200;
            const float yf = (float)(ly0 + yy);
            const float* fb = fbase + px;
            float f[8][4];
#pragma unroll
            for (int c = 0; c < 8; c++) {
                const float4 t = *reinterpret_cast<const float4*>(fb + c * HW);
                f[c][0] = t.x; f[c][1] = t.y; f[c][2] = t.z; f[c][3] = t.w;
            }
#pragma unroll
            for (int o = 0; o < 8; o++) {
                const float pre = A0[o] + Ay[o] * yf;
                float hv[4];
#pragma unroll
                for (int p = 0; p < 4; p++) {
                    const float xf = (float)(x + p);
                    float a = pre + Ax[o] * xf;
#pragma unroll
                    for (int c = 0; c < 8; c++) a += Wf[o * 8 + c] * f[c][p];
                    hv[p] = fmaxf(a, 0.0f);
                }
                *reinterpret_cast<float4*>(&hbuf[o * (SQUADS * 4) + tid * 4]) =
                    make_float4(hv[0], hv[1], hv[2], hv[3]);
            }
        }
        __syncthreads();

        // ---------- pass B: layer1 + relu + layer2 -> slog ----------
        MEMFENCE;                                // keep w1 pass-local
        float w1[64];
#pragma unroll
        for (int k = 0; k < 64; k++) w1[k] = pp[80 + k];
#pragma unroll
        for (int k = 0; k < 64; k++) PINS(w1[k]);
        float w2[8], b1[8], b2;
#pragma unroll
        for (int k = 0; k < 8; k++) { w2[k] = pp[144 + k]; b1[k] = pp[160 + k]; }
        b2 = pp[168];
#pragma unroll
        for (int k = 0; k < 8; k++) { PINV(w2[k]); PINV(b1[k]); }
        PINV(b2);

        if (act) {
            float h[8][4];
#pragma unroll
            for (int c = 0; c < 8; c++) {
                const float4 t = *reinterpret_cast<const float4*>(
                    &hbuf[c * (SQUADS * 4) + tid * 4]);
                h[c][0] = t.x; h[c][1] = t.y; h[c][2] = t.z; h[c][3] = t.w;
            }
            float o4[4];
#pragma unroll
            for (int p = 0; p < 4; p++) {
                float g[8];
#pragma unroll
                for (int o = 0; o < 8; o++) {
                    float a = b1[o];
#pragma unroll
                    for (int c = 0; c < 8; c++) a += w1[o * 8 + c] * h[c][p];
                    g[o] = fmaxf(a, 0.0f);
                }
                float lg = b2;
#pragma unroll
                for (int c = 0; c < 8; c++) lg += w2[c] * g[c];
                o4[p] = lg;
            }
            *reinterpret_cast<float4*>(&slog[q * 4]) =
                make_float4(o4[0], o4[1], o4[2], o4[3]);
        }
        __syncthreads();                         // hbuf reused next strip; slog ready
    }
}

// ---- per-tile bilinear-up + sigmoid + dice partials (identical to verified) ----
__device__ __forceinline__ void dice_tile(
    const float* __restrict__ slog, const float* __restrict__ gtn,
    int oy0, int ly0, int lycnt, int tid,
    float& aI, float& aS, float& aT)
{
    const float sy = 135.0f / 271.0f;
    const float sx = 199.0f / 399.0f;
    for (int g4 = tid; g4 < TROWS * (OW / 4); g4 += 256) {
        const int ry = g4 / 100;
        const int gx = (g4 - ry * 100) * 4;
        const int oy = oy0 + ry;
        const float ysf = (float)oy * sy;
        const int y0 = (int)ysf;
        const float wy = ysf - (float)y0;
        const int y1 = (y0 + 1 > Hh - 1) ? (Hh - 1) : (y0 + 1);
        int r0i = y0 - ly0, r1i = y1 - ly0;
        r0i = r0i < 0 ? 0 : (r0i > lycnt - 1 ? lycnt - 1 : r0i);
        r1i = r1i < 0 ? 0 : (r1i > lycnt - 1 ? lycnt - 1 : r1i);
        const float* s0 = &slog[r0i * Ww];
        const float* s1 = &slog[r1i * Ww];

        const float4 t4 = *reinterpret_cast<const float4*>(gtn + ry * OW + gx);
        const float tv[4] = { t4.x, t4.y, t4.z, t4.w };
#pragma unroll
        for (int p = 0; p < 4; p++) {
            const int ox = gx + p;
            const float xsf = (float)ox * sx;
            const int x0 = (int)xsf;
            const float wx = xsf - (float)x0;
            const int x1 = (x0 + 1 > Ww - 1) ? (Ww - 1) : (x0 + 1);
            const float v00 = s0[x0];
            const float v01 = s0[x1];
            const float v10 = s1[x0];
            const float v11 = s1[x1];
            const float top = v00 + wx * (v01 - v00);
            const float bot = v10 + wx * (v11 - v10);
            const float v   = top + wy * (bot - top);
            const float s   = __fdividef(1.0f, 1.0f + __expf(-v));
            aI += s * tv[p];
            aS += s * s;
            aT += tv[p];
        }
    }
}

// Affine precompute only (24 resident VGPRs) — matrices stay pass-local.
#define LOAD_AFFINE                                                             \
    const float ix = iloc[2 * n + 0];                                           \
    const float iy = iloc[2 * n + 1];                                           \
    const int   im = iminds[n];                                                 \
    const float invsoi = 1.0f / (float)(64 << lvls[n]);                         \
    const float* pp = pars + n * NPAR;                                          \
    float A0[8], Ax[8], Ay[8];                                                  \
    _Pragma("unroll")                                                           \
    for (int o = 0; o < 8; o++) {                                               \
        const float wx0 = pp[o * 10 + 0];                                       \
        const float wy0 = pp[o * 10 + 1];                                       \
        Ax[o] = -8.0f * invsoi * wx0;                                           \
        Ay[o] = -8.0f * invsoi * wy0;                                           \
        A0[o] = pp[152 + o] + (wx0 * (ix - 4.0f) + wy0 * (iy - 4.0f)) * invsoi; \
    }                                                                           \
    _Pragma("unroll")                                                           \
    for (int o = 0; o < 8; o++) { PINV(A0[o]); PINV(Ax[o]); PINV(Ay[o]); }

// ---------------- Fused: MLP -> LDS logits -> dice partials ----------------
__global__ __launch_bounds__(256, 3) void dmh_tile(
    const float* __restrict__ feats,
    const float* __restrict__ pars,
    const float* __restrict__ iloc,
    const float* __restrict__ gt,
    const int* __restrict__ iminds,
    const int* __restrict__ lvls,
    float* __restrict__ part)
{
    __shared__ float slog[LROWS * Ww];
    __shared__ float hbuf[8 * SQUADS * 4];
    __shared__ float sred[12];

    const int n    = blockIdx.y;
    const int tile = blockIdx.x;
    const int tid  = threadIdx.x;

    LOAD_AFFINE

    const float sy = 135.0f / 271.0f;
    const int oy0 = tile * TROWS;
    const int ly0 = (int)((float)oy0 * sy);
    int lyL = (int)((float)(oy0 + TROWS - 1) * sy) + 1;
    if (lyL > Hh - 1) lyL = Hh - 1;
    const int lycnt = lyL - ly0 + 1;

    const float* fb0 = feats + (size_t)im * (CIN * HW);
    mlp_tile_2pq(slog, hbuf, fb0, pp, ly0, lycnt, tid, A0, Ax, Ay);
    // trailing __syncthreads in the strip loop: slog is ready

    float aI = 0.0f, aS = 0.0f, aT = 0.0f;
    const float* gtn = gt + (size_t)n * (OH * OW) + (size_t)oy0 * OW;
    dice_tile(slog, gtn, oy0, ly0, lycnt, tid, aI, aS, aT);

#pragma unroll
    for (int off = 32; off > 0; off >>= 1) {
        aI += __shfl_down(aI, off, 64);
        aS += __shfl_down(aS, off, 64);
        aT += __shfl_down(aT, off, 64);
    }
    const int wv = tid >> 6;
    if ((tid & 63) == 0) {
        sred[wv * 3 + 0] = aI;
        sred[wv * 3 + 1] = aS;
        sred[wv * 3 + 2] = aT;
    }
    __syncthreads();
    if (tid == 0) {
        float* pt = part + (size_t)(n * NTILES + tile) * 3;
        pt[0] = sred[0] + sred[3] + sred[6] + sred[9];
        pt[1] = sred[1] + sred[4] + sred[7] + sred[10];
        pt[2] = sred[2] + sred[5] + sred[8] + sred[11];
    }
}

__global__ __launch_bounds__(256) void dmh_fin2(const float* __restrict__ part,
                                                float* __restrict__ out)
{
    const int i = blockIdx.x * 256 + threadIdx.x;
    if (i < NINST) {
        float I = 0.0f, S = 0.0f, T = 0.0f;
#pragma unroll
        for (int t = 0; t < NTILES; t++) {
            const float* pt = part + (size_t)(i * NTILES + t) * 3;
            I += pt[0]; S += pt[1]; T += pt[2];
        }
        out[i] = 1.0f - 2.0f * I / (S + T + 1e-5f);
    }
}

// ---- workspace-free fallback: one block per instance, loops over tiles ----
__global__ __launch_bounds__(256, 3) void dmh_one(
    const float* __restrict__ feats,
    const float* __restrict__ pars,
    const float* __restrict__ iloc,
    const float* __restrict__ gt,
    const int* __restrict__ iminds,
    const int* __restrict__ lvls,
    float* __restrict__ out)
{
    __shared__ float slog[LROWS * Ww];
    __shared__ float hbuf[8 * SQUADS * 4];
    __shared__ float sred[12];

    const int n   = blockIdx.x;
    const int tid = threadIdx.x;

    LOAD_AFFINE

    const float sy = 135.0f / 271.0f;
    const float* fb0 = feats + (size_t)im * (CIN * HW);

    float aI = 0.0f, aS = 0.0f, aT = 0.0f;
    for (int tile = 0; tile < NTILES; tile++) {
        const int oy0 = tile * TROWS;
        const int ly0 = (int)((float)oy0 * sy);
        int lyL = (int)((float)(oy0 + TROWS - 1) * sy) + 1;
        if (lyL > Hh - 1) lyL = Hh - 1;
        const int lycnt = lyL - ly0 + 1;

        mlp_tile_2pq(slog, hbuf, fb0, pp, ly0, lycnt, tid, A0, Ax, Ay);
        const float* gtn = gt + (size_t)n * (OH * OW) + (size_t)oy0 * OW;
        dice_tile(slog, gtn, oy0, ly0, lycnt, tid, aI, aS, aT);
        __syncthreads();  // slog reused next tile
    }

#pragma unroll
    for (int off = 32; off > 0; off >>= 1) {
        aI += __shfl_down(aI, off, 64);
        aS += __shfl_down(aS, off, 64);
        aT += __shfl_down(aT, off, 64);
    }
    const int wv = tid >> 6;
    if ((tid & 63) == 0) {
        sred[wv * 3 + 0] = aI;
        sred[wv * 3 + 1] = aS;
        sred[wv * 3 + 2] = aT;
    }
    __syncthreads();
    if (tid == 0) {
        const float I = sred[0] + sred[3] + sred[6] + sred[9];
        const float S = sred[1] + sred[4] + sred[7] + sred[10];
        const float T = sred[2] + sred[5] + sred[8] + sred[11];
        out[n] = 1.0f - 2.0f * I / (S + T + 1e-5f);
    }
}

extern "C" void kernel_launch(void* const* d_in, const int* in_sizes, int n_in,
                              void* d_out, int out_size, void* d_ws, size_t ws_size,
                              hipStream_t stream) {
    const float* feats  = (const float*)d_in[0];
    const float* pars   = (const float*)d_in[1];
    const float* iloc   = (const float*)d_in[2];
    const float* gt     = (const float*)d_in[3];
    const int*   iminds = (const int*)d_in[4];
    const int*   lvls   = (const int*)d_in[5];

    if (ws_size >= PART_BYTES) {
        float* part = (float*)d_ws;
        dim3 g(NTILES, NINST);
        dmh_tile<<<g, 256, 0, stream>>>(feats, pars, iloc, gt, iminds, lvls, part);
        dmh_fin2<<<(NINST + 255) / 256, 256, 0, stream>>>(part, (float*)d_out);
    } else {
        dmh_one<<<NINST, 256, 0, stream>>>(feats, pars, iloc, gt, iminds, lvls,
                                           (float*)d_out);
    }
}

// Round 5
// 383.027 us; speedup vs baseline: 1.5833x; 1.0464x over previous
//
#include <hip/hip_runtime.h>
#include <math.h>

#define NIMG 8
#define CIN 8
#define Hh 136
#define Ww 200
#define HW (Hh * Ww)
#define OH 272
#define OW 400
#define NINST 512
#define NPAR 169
#define TROWS 34
#define NTILES 8
#define LROWS 19
#define SPX 512                         // strip pixels (2 px per thread)
#define PART_BYTES ((size_t)NINST * NTILES * 3 * 4)

#define PINV(x) asm volatile("" : "+v"(x))
#define PINS(x) asm volatile("" : "+s"(x))
#define MEMFENCE asm volatile("" ::: "memory")

// ---- two-pass MLP over flat 512-px strips (2 px/thread) ----
// R4 post-mortem: latency-bound at 3 blocks/CU; hbuf(32K) was the LDS hog.
// 512-px strips halve hbuf -> 31.6 KB LDS -> 5 blocks/CU (~62% occ cap).
// Pass A: layer0 (Wf in SGPRs) -> hbuf. Pass B: layer1+2 (w1 in SGPRs) -> slog.
// Wf/w1 never live together (SGPR wave budget ~102). Pixel pairs never
// straddle rows (Ww even). FP trees byte-identical to R0-R4 (absmax 0.0).
__device__ __forceinline__ void mlp_tile_2p2(
    float* __restrict__ slog, float* __restrict__ hbuf,
    const float* __restrict__ fb0, const float* __restrict__ pp,
    int ly0, int lycnt, int tid,
    const float (&A0)[8], const float (&Ax)[8], const float (&Ay)[8])
{
    const int tpx = lycnt * Ww;                 // tile pixels (<= 3800)
    const float* fbase = fb0 + ly0 * Ww;        // contiguous region per plane

    for (int p0 = 0; p0 < tpx; p0 += SPX) {
        const int px  = p0 + tid * 2;
        const bool act = px < tpx;

        // ---------- pass A: layer0 + relu -> hbuf ----------
        MEMFENCE;                                // keep Wf pass-local
        float Wf[64];
#pragma unroll
        for (int o = 0; o < 8; o++)
#pragma unroll
            for (int c = 0; c < 8; c++) Wf[o * 8 + c] = pp[o * 10 + 2 + c];
#pragma unroll
        for (int i = 0; i < 64; i++) PINS(Wf[i]);

        if (act) {
            const int yy = px / 200;
            const int x  = px - yy * 200;
            const float yf = (float)(ly0 + yy);
            const float* fb = fbase + px;
            float f[8][2];
#pragma unroll
            for (int c = 0; c < 8; c++) {
                const float2 t = *reinterpret_cast<const float2*>(fb + c * HW);
                f[c][0] = t.x; f[c][1] = t.y;
            }
#pragma unroll
            for (int o = 0; o < 8; o++) {
                const float pre = A0[o] + Ay[o] * yf;
                float hv[2];
#pragma unroll
                for (int p = 0; p < 2; p++) {
                    const float xf = (float)(x + p);
                    float a = pre + Ax[o] * xf;
#pragma unroll
                    for (int c = 0; c < 8; c++) a += Wf[o * 8 + c] * f[c][p];
                    hv[p] = fmaxf(a, 0.0f);
                }
                *reinterpret_cast<float2*>(&hbuf[o * SPX + tid * 2]) =
                    make_float2(hv[0], hv[1]);
            }
        }
        __syncthreads();

        // ---------- pass B: layer1 + relu + layer2 -> slog ----------
        MEMFENCE;                                // keep w1 pass-local
        float w1[64];
#pragma unroll
        for (int k = 0; k < 64; k++) w1[k] = pp[80 + k];
#pragma unroll
        for (int k = 0; k < 64; k++) PINS(w1[k]);
        float w2[8], b1[8], b2;
#pragma unroll
        for (int k = 0; k < 8; k++) { w2[k] = pp[144 + k]; b1[k] = pp[160 + k]; }
        b2 = pp[168];
#pragma unroll
        for (int k = 0; k < 8; k++) { PINV(w2[k]); PINV(b1[k]); }
        PINV(b2);

        if (act) {
            float h[8][2];
#pragma unroll
            for (int c = 0; c < 8; c++) {
                const float2 t = *reinterpret_cast<const float2*>(
                    &hbuf[c * SPX + tid * 2]);
                h[c][0] = t.x; h[c][1] = t.y;
            }
            float o2[2];
#pragma unroll
            for (int p = 0; p < 2; p++) {
                float g[8];
#pragma unroll
                for (int o = 0; o < 8; o++) {
                    float a = b1[o];
#pragma unroll
                    for (int c = 0; c < 8; c++) a += w1[o * 8 + c] * h[c][p];
                    g[o] = fmaxf(a, 0.0f);
                }
                float lg = b2;
#pragma unroll
                for (int c = 0; c < 8; c++) lg += w2[c] * g[c];
                o2[p] = lg;
            }
            *reinterpret_cast<float2*>(&slog[px]) = make_float2(o2[0], o2[1]);
        }
        __syncthreads();                         // hbuf reused next strip
    }
}

// ---- per-tile bilinear-up + sigmoid + dice partials (identical to verified) ----
__device__ __forceinline__ void dice_tile(
    const float* __restrict__ slog, const float* __restrict__ gtn,
    int oy0, int ly0, int lycnt, int tid,
    float& aI, float& aS, float& aT)
{
    const float sy = 135.0f / 271.0f;
    const float sx = 199.0f / 399.0f;
    for (int g4 = tid; g4 < TROWS * (OW / 4); g4 += 256) {
        const int ry = g4 / 100;
        const int gx = (g4 - ry * 100) * 4;
        const int oy = oy0 + ry;
        const float ysf = (float)oy * sy;
        const int y0 = (int)ysf;
        const float wy = ysf - (float)y0;
        const int y1 = (y0 + 1 > Hh - 1) ? (Hh - 1) : (y0 + 1);
        int r0i = y0 - ly0, r1i = y1 - ly0;
        r0i = r0i < 0 ? 0 : (r0i > lycnt - 1 ? lycnt - 1 : r0i);
        r1i = r1i < 0 ? 0 : (r1i > lycnt - 1 ? lycnt - 1 : r1i);
        const float* s0 = &slog[r0i * Ww];
        const float* s1 = &slog[r1i * Ww];

        const float4 t4 = *reinterpret_cast<const float4*>(gtn + ry * OW + gx);
        const float tv[4] = { t4.x, t4.y, t4.z, t4.w };
#pragma unroll
        for (int p = 0; p < 4; p++) {
            const int ox = gx + p;
            const float xsf = (float)ox * sx;
            const int x0 = (int)xsf;
            const float wx = xsf - (float)x0;
            const int x1 = (x0 + 1 > Ww - 1) ? (Ww - 1) : (x0 + 1);
            const float v00 = s0[x0];
            const float v01 = s0[x1];
            const float v10 = s1[x0];
            const float v11 = s1[x1];
            const float top = v00 + wx * (v01 - v00);
            const float bot = v10 + wx * (v11 - v10);
            const float v   = top + wy * (bot - top);
            const float s   = __fdividef(1.0f, 1.0f + __expf(-v));
            aI += s * tv[p];
            aS += s * s;
            aT += tv[p];
        }
    }
}

// Affine precompute only (24 resident VGPRs) — matrices stay pass-local.
#define LOAD_AFFINE                                                             \
    const float ix = iloc[2 * n + 0];                                           \
    const float iy = iloc[2 * n + 1];                                           \
    const int   im = iminds[n];                                                 \
    const float invsoi = 1.0f / (float)(64 << lvls[n]);                         \
    const float* pp = pars + n * NPAR;                                          \
    float A0[8], Ax[8], Ay[8];                                                  \
    _Pragma("unroll")                                                           \
    for (int o = 0; o < 8; o++) {                                               \
        const float wx0 = pp[o * 10 + 0];                                       \
        const float wy0 = pp[o * 10 + 1];                                       \
        Ax[o] = -8.0f * invsoi * wx0;                                           \
        Ay[o] = -8.0f * invsoi * wy0;                                           \
        A0[o] = pp[152 + o] + (wx0 * (ix - 4.0f) + wy0 * (iy - 4.0f)) * invsoi; \
    }                                                                           \
    _Pragma("unroll")                                                           \
    for (int o = 0; o < 8; o++) { PINV(A0[o]); PINV(Ax[o]); PINV(Ay[o]); }

// ---------------- Fused: MLP -> LDS logits -> dice partials ----------------
__global__ __launch_bounds__(256, 5) void dmh_tile(
    const float* __restrict__ feats,
    const float* __restrict__ pars,
    const float* __restrict__ iloc,
    const float* __restrict__ gt,
    const int* __restrict__ iminds,
    const int* __restrict__ lvls,
    float* __restrict__ part)
{
    __shared__ float slog[LROWS * Ww];
    __shared__ float hbuf[8 * SPX];
    __shared__ float sred[12];

    const int n    = blockIdx.y;
    const int tile = blockIdx.x;
    const int tid  = threadIdx.x;

    LOAD_AFFINE

    const float sy = 135.0f / 271.0f;
    const int oy0 = tile * TROWS;
    const int ly0 = (int)((float)oy0 * sy);
    int lyL = (int)((float)(oy0 + TROWS - 1) * sy) + 1;
    if (lyL > Hh - 1) lyL = Hh - 1;
    const int lycnt = lyL - ly0 + 1;

    const float* fb0 = feats + (size_t)im * (CIN * HW);
    mlp_tile_2p2(slog, hbuf, fb0, pp, ly0, lycnt, tid, A0, Ax, Ay);
    // trailing __syncthreads in the strip loop: slog is ready

    float aI = 0.0f, aS = 0.0f, aT = 0.0f;
    const float* gtn = gt + (size_t)n * (OH * OW) + (size_t)oy0 * OW;
    dice_tile(slog, gtn, oy0, ly0, lycnt, tid, aI, aS, aT);

#pragma unroll
    for (int off = 32; off > 0; off >>= 1) {
        aI += __shfl_down(aI, off, 64);
        aS += __shfl_down(aS, off, 64);
        aT += __shfl_down(aT, off, 64);
    }
    const int wv = tid >> 6;
    if ((tid & 63) == 0) {
        sred[wv * 3 + 0] = aI;
        sred[wv * 3 + 1] = aS;
        sred[wv * 3 + 2] = aT;
    }
    __syncthreads();
    if (tid == 0) {
        float* pt = part + (size_t)(n * NTILES + tile) * 3;
        pt[0] = sred[0] + sred[3] + sred[6] + sred[9];
        pt[1] = sred[1] + sred[4] + sred[7] + sred[10];
        pt[2] = sred[2] + sred[5] + sred[8] + sred[11];
    }
}

__global__ __launch_bounds__(256) void dmh_fin2(const float* __restrict__ part,
                                                float* __restrict__ out)
{
    const int i = blockIdx.x * 256 + threadIdx.x;
    if (i < NINST) {
        float I = 0.0f, S = 0.0f, T = 0.0f;
#pragma unroll
        for (int t = 0; t < NTILES; t++) {
            const float* pt = part + (size_t)(i * NTILES + t) * 3;
            I += pt[0]; S += pt[1]; T += pt[2];
        }
        out[i] = 1.0f - 2.0f * I / (S + T + 1e-5f);
    }
}

// ---- workspace-free fallback: one block per instance, loops over tiles ----
__global__ __launch_bounds__(256, 5) void dmh_one(
    const float* __restrict__ feats,
    const float* __restrict__ pars,
    const float* __restrict__ iloc,
    const float* __restrict__ gt,
    const int* __restrict__ iminds,
    const int* __restrict__ lvls,
    float* __restrict__ out)
{
    __shared__ float slog[LROWS * Ww];
    __shared__ float hbuf[8 * SPX];
    __shared__ float sred[12];

    const int n   = blockIdx.x;
    const int tid = threadIdx.x;

    LOAD_AFFINE

    const float sy = 135.0f / 271.0f;
    const float* fb0 = feats + (size_t)im * (CIN * HW);

    float aI = 0.0f, aS = 0.0f, aT = 0.0f;
    for (int tile = 0; tile < NTILES; tile++) {
        const int oy0 = tile * TROWS;
        const int ly0 = (int)((float)oy0 * sy);
        int lyL = (int)((float)(oy0 + TROWS - 1) * sy) + 1;
        if (lyL > Hh - 1) lyL = Hh - 1;
        const int lycnt = lyL - ly0 + 1;

        mlp_tile_2p2(slog, hbuf, fb0, pp, ly0, lycnt, tid, A0, Ax, Ay);
        const float* gtn = gt + (size_t)n * (OH * OW) + (size_t)oy0 * OW;
        dice_tile(slog, gtn, oy0, ly0, lycnt, tid, aI, aS, aT);
        __syncthreads();  // slog reused next tile
    }

#pragma unroll
    for (int off = 32; off > 0; off >>= 1) {
        aI += __shfl_down(aI, off, 64);
        aS += __shfl_down(aS, off, 64);
        aT += __shfl_down(aT, off, 64);
    }
    const int wv = tid >> 6;
    if ((tid & 63) == 0) {
        sred[wv * 3 + 0] = aI;
        sred[wv * 3 + 1] = aS;
        sred[wv * 3 + 2] = aT;
    }
    __syncthreads();
    if (tid == 0) {
        const float I = sred[0] + sred[3] + sred[6] + sred[9];
        const float S = sred[1] + sred[4] + sred[7] + sred[10];
        const float T = sred[2] + sred[5] + sred[8] + sred[11];
        out[n] = 1.0f - 2.0f * I / (S + T + 1e-5f);
    }
}

extern "C" void kernel_launch(void* const* d_in, const int* in_sizes, int n_in,
                              void* d_out, int out_size, void* d_ws, size_t ws_size,
                              hipStream_t stream) {
    const float* feats  = (const float*)d_in[0];
    const float* pars   = (const float*)d_in[1];
    const float* iloc   = (const float*)d_in[2];
    const float* gt     = (const float*)d_in[3];
    const int*   iminds = (const int*)d_in[4];
    const int*   lvls   = (const int*)d_in[5];

    if (ws_size >= PART_BYTES) {
        float* part = (float*)d_ws;
        dim3 g(NTILES, NINST);
        dmh_tile<<<g, 256, 0, stream>>>(feats, pars, iloc, gt, iminds, lvls, part);
        dmh_fin2<<<(NINST + 255) / 256, 256, 0, stream>>>(part, (float*)d_out);
    } else {
        dmh_one<<<NINST, 256, 0, stream>>>(feats, pars, iloc, gt, iminds, lvls,
                                           (float*)d_out);
    }
}